// Round 18
// baseline (434.691 us; speedup 1.0000x reference)
//
#include <hip/hip_runtime.h>

#define DM    128
#define NHEAD 2
#define HIDC  64
#define OUTC  32
#define NG    64
#define EPS   1e-5f
#define DCAP  64     // fixed per-dst adjacency capacity (Poisson(16), 12 sigma)

typedef __attribute__((ext_vector_type(8))) short bf16x8;
typedef __attribute__((ext_vector_type(4))) float f32x4;

__device__ __forceinline__ unsigned short f2bf(float f) {
    union { float f; unsigned int u; } v; v.f = f;
    unsigned int r = v.u + 0x7fffu + ((v.u >> 16) & 1u);   // RNE
    return (unsigned short)(r >> 16);
}
__device__ __forceinline__ float bflo(unsigned int u) {
    union { unsigned int u; float f; } v; v.u = u << 16; return v.f;
}
__device__ __forceinline__ float bfhi(unsigned int u) {
    union { unsigned int u; float f; } v; v.u = u & 0xffff0000u; return v.f;
}

// ---------------------------------------------------------------------------
// Prep kernel: [0,24) wprep x3 | [24,24+xb) xprep | cursor-zero | sums-zero.
// ---------------------------------------------------------------------------
__global__ __launch_bounds__(256) void prep_kernel(
    const float* __restrict__ W1, const float* __restrict__ Wskip,
    const float* __restrict__ W2,
    unsigned short* __restrict__ wf1, unsigned short* __restrict__ wfs,
    unsigned short* __restrict__ wf2,
    const float* __restrict__ x, unsigned short* __restrict__ xbf, int total,
    int xb, int* __restrict__ cursor, int N,
    float* __restrict__ sums, int sums_n, int cz)
{
    const int b = blockIdx.x;
    if (b < 24) {
        const float* W = b < 8 ? W1 : (b < 16 ? Wskip : W2);
        unsigned short* WF = b < 8 ? wf1 : (b < 16 ? wfs : wf2);
        const int idx = (b & 7) * 256 + threadIdx.x;    // 0..2047
        const int nt   = idx >> 8;
        const int ks   = (idx >> 6) & 3;
        const int lane = idx & 63;
        const int c    = nt * 16 + (lane & 15);
        const int k0   = ks * 32 + (lane >> 4) * 8;
        bf16x8 f;
#pragma unroll
        for (int j = 0; j < 8; ++j)
            f[j] = (short)f2bf(W[(k0 + j) * DM + c]);
        ((bf16x8*)WF)[idx] = f;
    } else if (b < 24 + xb) {
        const int i = ((b - 24) * 256 + threadIdx.x) * 4;
        if (i < total) {
            const float4 v = *(const float4*)&x[i];
            ushort4 o;
            o.x = f2bf(v.x); o.y = f2bf(v.y); o.z = f2bf(v.z); o.w = f2bf(v.w);
            *(ushort4*)&xbf[i] = o;
        }
    } else if (b < 24 + xb + cz) {
        const int i0 = ((b - 24 - xb) * 256 + threadIdx.x) * 4;
#pragma unroll
        for (int k = 0; k < 4; ++k)
            if (i0 + k < N) cursor[i0 + k] = 0;
    } else {
        const int i0 = ((b - 24 - xb - cz) * 256 + threadIdx.x) * 4;
#pragma unroll
        for (int k = 0; k < 4; ++k)
            if (i0 + k < sums_n) sums[i0 + k] = 0.f;
    }
}

// ---------------------------------------------------------------------------
// MFMA GEMM body: A bf16 row-major, B pre-swizzled frags, bf16 output.
// ---------------------------------------------------------------------------
__device__ __forceinline__ void gemm_body(
    const unsigned short* __restrict__ Xbf, int N,
    const unsigned short* __restrict__ Wfrag,
    const float* __restrict__ bias,
    const float* __restrict__ att_src,
    const float* __restrict__ att_dst,
    unsigned short* __restrict__ Cbf,
    float* __restrict__ a_src,
    float* __restrict__ a_dst,
    int bid, int nblocks)
{
    const int lane = threadIdx.x & 63;
    const int wave = threadIdx.x >> 6;
    const int col  = lane & 15;
    const int kgrp = lane >> 4;

    bf16x8 bfrag[8][4];
    {
        const bf16x8* wf = (const bf16x8*)Wfrag;
#pragma unroll
        for (int nt = 0; nt < 8; ++nt)
#pragma unroll
            for (int ks = 0; ks < 4; ++ks)
                bfrag[nt][ks] = wf[(nt * 4 + ks) * 64 + lane];
    }

    float bcol[8];
#pragma unroll
    for (int nt = 0; nt < 8; ++nt)
        bcol[nt] = bias ? bias[nt * 16 + col] : 0.f;

    float as_c[8], ad_c[8];
    if (att_src) {
#pragma unroll
        for (int nt = 0; nt < 8; ++nt) {
            as_c[nt] = att_src[nt * 16 + col];
            ad_c[nt] = att_dst[nt * 16 + col];
        }
    }

    const int ntiles = (N + 15) >> 4;
    for (int tile = bid * 4 + wave; tile < ntiles; tile += nblocks * 4) {
        const int row0 = tile * 16;

        f32x4 acc[8];
#pragma unroll
        for (int nt = 0; nt < 8; ++nt) acc[nt] = (f32x4){0.f, 0.f, 0.f, 0.f};

        const int r = min(row0 + col, N - 1);
#pragma unroll
        for (int ks = 0; ks < 4; ++ks) {
            const int k0 = ks * 32 + kgrp * 8;
            const bf16x8 af = *(const bf16x8*)&Xbf[(size_t)r * DM + k0];
#pragma unroll
            for (int nt = 0; nt < 8; ++nt)
                acc[nt] = __builtin_amdgcn_mfma_f32_16x16x32_bf16(
                              af, bfrag[nt][ks], acc[nt], 0, 0, 0);
        }

        float dots[4][2], dotd[4][2];
        if (att_src) {
#pragma unroll
            for (int reg = 0; reg < 4; ++reg) {
                dots[reg][0] = dots[reg][1] = 0.f;
                dotd[reg][0] = dotd[reg][1] = 0.f;
            }
        }
#pragma unroll
        for (int reg = 0; reg < 4; ++reg) {
            const int row = row0 + kgrp * 4 + reg;
            const bool ok = row < N;
#pragma unroll
            for (int nt = 0; nt < 8; ++nt) {
                const float o = acc[nt][reg] + bcol[nt];
                if (ok) Cbf[(size_t)row * DM + nt * 16 + col] = f2bf(o);
                if (att_src) {
                    dots[reg][nt >> 2] += o * as_c[nt];
                    dotd[reg][nt >> 2] += o * ad_c[nt];
                }
            }
        }
        if (att_src) {
#pragma unroll
            for (int reg = 0; reg < 4; ++reg) {
#pragma unroll
                for (int h = 0; h < 2; ++h) {
                    float vs = dots[reg][h], vd = dotd[reg][h];
#pragma unroll
                    for (int off = 8; off; off >>= 1) {
                        vs += __shfl_xor(vs, off);
                        vd += __shfl_xor(vd, off);
                    }
                    const int row = row0 + kgrp * 4 + reg;
                    if (col == 0 && row < N) {
                        a_src[row * NHEAD + h] = vs;
                        a_dst[row * NHEAD + h] = vd;
                    }
                }
            }
        }
    }
}

// ---------------------------------------------------------------------------
// Mega kernel: [0,256) H = x@W1 (+att dots) | [256,512) Skip | [512,..) scatter.
// ---------------------------------------------------------------------------
__global__ __launch_bounds__(256) void gemm_scatter_kernel(
    const unsigned short* __restrict__ Xbf, int N,
    const unsigned short* __restrict__ wf1,
    const unsigned short* __restrict__ wfs,
    const float* __restrict__ bskip,
    const float* __restrict__ as1, const float* __restrict__ ad1,
    unsigned short* __restrict__ Hbuf, unsigned short* __restrict__ Skipbf,
    float* __restrict__ a_src, float* __restrict__ a_dst,
    const int* __restrict__ ei, int E,
    int* __restrict__ cursor, unsigned short* __restrict__ col)
{
    const int b = blockIdx.x;
    if (b < 256) {
        gemm_body(Xbf, N, wf1, nullptr, as1, ad1, Hbuf, a_src, a_dst, b, 256);
    } else if (b < 512) {
        gemm_body(Xbf, N, wfs, bskip, nullptr, nullptr, Skipbf,
                  nullptr, nullptr, b - 256, 256);
    } else {
        const int e = (b - 512) * 256 + threadIdx.x;
        if (e < E) {
            const int d = ei[E + e];
            const int k = atomicAdd(&cursor[d], 1);
            if (k < DCAP) col[d * DCAP + k] = (unsigned short)ei[e];
        }
    }
}

// layer 2 GEMM
__global__ __launch_bounds__(256) void mfma_gemm_kernel(
    const unsigned short* __restrict__ Xbf, int N,
    const unsigned short* __restrict__ Wfrag,
    const float* __restrict__ att_src,
    const float* __restrict__ att_dst,
    unsigned short* __restrict__ Cbf,
    float* __restrict__ a_src,
    float* __restrict__ a_dst)
{
    gemm_body(Xbf, N, Wfrag, nullptr, att_src, att_dst, Cbf,
              a_src, a_dst, blockIdx.x, gridDim.x);
}

// ---------------------------------------------------------------------------
// XCD-channel-sliced GAT aggregation. Block b: slice cs = b&7 (16 channels),
// node-group j = b>>3. blockIdx%8 rides the round-robin XCD mapping, so each
// XCD touches only a 32B sub-slice of every H row -> compulsory L2 fetch drops
// 8x -> ~2x-per-line. 4 waves/block, 2 nodes/wave. Lane = edge-slot (lane>>3)
// x channel-pair (lane&7). Writes pre-LN f32 v = agg/den + bias.
// ---------------------------------------------------------------------------
__global__ __launch_bounds__(256) void agg_slice_kernel(
    const int* __restrict__ deg,
    const unsigned short* __restrict__ col,
    const unsigned short* __restrict__ H,     // bf16
    const float* __restrict__ a_src,
    const float* __restrict__ a_dst,
    const float* __restrict__ bias,
    float* __restrict__ vbuf,                 // f32 pre-LN out
    int N)
{
    const int cs   = blockIdx.x & 7;
    const int j    = blockIdx.x >> 3;
    const int w    = threadIdx.x >> 6;
    const int lane = threadIdx.x & 63;
    const int ei8  = lane >> 3;
    const int cl   = lane & 7;
    const int head = cs >> 2;
    const int cbase = cs * 16 + cl * 2;

#pragma unroll
    for (int k = 0; k < 2; ++k) {
        const int d = j * 8 + w * 2 + k;
        if (d >= N) break;

        const float ad_h = a_dst[d * NHEAD + head];
        float e0 = a_src[d * NHEAD + head] + ad_h;
        e0 = e0 > 0.f ? e0 : 0.2f * e0;
        const float wself = __expf(e0);

        float den_p = 0.f, ax = 0.f, ay = 0.f;
        const int dg = min(deg[d], DCAP);
        const int p0 = d * DCAP;
        for (int base = 0; base < dg; base += 8) {
            float we = 0.f;
            unsigned int u = 0;
            const int ee = base + ei8;
            if (ee < dg) {
                const int s = (int)col[p0 + ee];
                float a = a_src[s * NHEAD + head] + ad_h;
                a = a > 0.f ? a : 0.2f * a;
                we = __expf(a);
                u = *(const unsigned int*)&H[(size_t)s * DM + cbase];
            }
            den_p += we;
            ax += we * bflo(u);
            ay += we * bfhi(u);
        }
        // reduce across the 8 edge-slot groups (channel cl preserved)
#pragma unroll
        for (int off = 8; off < 64; off <<= 1) {
            den_p += __shfl_xor(den_p, off);
            ax    += __shfl_xor(ax, off);
            ay    += __shfl_xor(ay, off);
        }
        if (ei8 == 0) {
            const unsigned int hu = *(const unsigned int*)&H[(size_t)d * DM + cbase];
            const float den = den_p + wself;
            const float rden = 1.f / den;
            const float vx = (ax + wself * bflo(hu)) * rden + bias[cbase];
            const float vy = (ay + wself * bfhi(hu)) * rden + bias[cbase + 1];
            *(float2*)&vbuf[(size_t)d * DM + cbase] = make_float2(vx, vy);
        }
    }
}

// ---------------------------------------------------------------------------
// LayerNorm kernel: v(f32) (+res bf16 pre-LN) -> LN -> ELU (+skip bf16) -> bf16.
// One wave per node, 2 per block.
// ---------------------------------------------------------------------------
__global__ __launch_bounds__(128) void ln_kernel(
    const float* __restrict__ v,
    const unsigned short* __restrict__ res,   // nullable bf16, pre-LN
    const float* __restrict__ lng,
    const float* __restrict__ lnb,
    const unsigned short* __restrict__ skip,  // nullable bf16, post-ELU
    unsigned short* __restrict__ obf,
    int N)
{
    const int wid  = threadIdx.x >> 6;
    const int d    = blockIdx.x * 2 + wid;
    if (d >= N) return;
    const int lane = threadIdx.x & 63;
    const int c2   = lane * 2;
    const size_t ibase = (size_t)d * DM + c2;

    float2 vv = *(const float2*)&v[ibase];
    if (res) {
        const unsigned int ru = *(const unsigned int*)&res[ibase];
        vv.x += bflo(ru); vv.y += bfhi(ru);
    }

    float sm = vv.x + vv.y;
#pragma unroll
    for (int off = 1; off < 64; off <<= 1) sm += __shfl_xor(sm, off);
    const float mean = sm * (1.f / DM);

    const float dx = vv.x - mean, dy = vv.y - mean;
    float s2 = dx * dx + dy * dy;
#pragma unroll
    for (int off = 1; off < 64; off <<= 1) s2 += __shfl_xor(s2, off);
    const float rstd = rsqrtf(s2 * (1.f / DM) + EPS);

    const float2 gv = *(const float2*)&lng[c2];
    const float2 bb = *(const float2*)&lnb[c2];
    float yx = dx * rstd * gv.x + bb.x;
    float yy = dy * rstd * gv.y + bb.y;
    yx = yx > 0.f ? yx : expm1f(yx);
    yy = yy > 0.f ? yy : expm1f(yy);
    if (skip) {
        const unsigned int su = *(const unsigned int*)&skip[ibase];
        yx += bflo(su); yy += bfhi(su);
    }
    const unsigned int pk = (unsigned int)f2bf(yx) |
                            ((unsigned int)f2bf(yy) << 16);
    *(unsigned int*)&obf[ibase] = pk;
}

// ---------------------------------------------------------------------------
// Global mean pool over bf16 emb: sorted batch -> register runs, few atomics.
// ---------------------------------------------------------------------------
__global__ void pool_kernel(const unsigned short* __restrict__ emb,
                            const int* __restrict__ batch, int N,
                            float* __restrict__ sums,
                            float* __restrict__ cnt)
{
    const int t = threadIdx.x;
    const int chunk = (N + gridDim.x - 1) / gridDim.x;
    const int n0 = blockIdx.x * chunk;
    const int n1 = min(N, n0 + chunk);
    if (n0 >= n1) return;

    int cur = batch[n0];
    float acc = 0.f;
    int count = 0;
    for (int n = n0; n < n1; ++n) {
        int b = batch[n];
        if (b != cur) {
            atomicAdd(&sums[cur * DM + t], acc);
            if (t == 0) atomicAdd(&cnt[cur], (float)count);
            acc = 0.f; count = 0; cur = b;
        }
        unsigned short h = emb[(size_t)n * DM + t];
        union { unsigned int u; float f; } v; v.u = ((unsigned int)h) << 16;
        acc += v.f;
        ++count;
    }
    atomicAdd(&sums[cur * DM + t], acc);
    if (t == 0) atomicAdd(&cnt[cur], (float)count);
}

// ---------------------------------------------------------------------------
// Head: graph_emb = sums/cnt; logits = ge @ Wfc + bfc; BatchNorm over graphs.
// ---------------------------------------------------------------------------
__global__ void head_kernel(const float* __restrict__ sums,
                            const float* __restrict__ cnt,
                            const float* __restrict__ Wfc,
                            const float* __restrict__ bfc,
                            const float* __restrict__ bn_g,
                            const float* __restrict__ bn_b,
                            float* __restrict__ out)
{
    __shared__ float ge[NG * DM];
    __shared__ float lg[NG * OUTC];
    __shared__ float mu[OUTC], inv[OUTC];
    const int t = threadIdx.x;

    for (int i = t; i < NG * DM; i += blockDim.x) {
        int g = i >> 7;
        ge[i] = sums[i] / fmaxf(cnt[g], 1.0f);
    }
    __syncthreads();

    for (int i = t; i < NG * OUTC; i += blockDim.x) {
        int g = i >> 5, o = i & (OUTC - 1);
        float acc = bfc[o];
#pragma unroll
        for (int k = 0; k < DM; ++k) acc += ge[g * DM + k] * Wfc[k * OUTC + o];
        lg[i] = acc;
    }
    __syncthreads();

    if (t < OUTC) {
        float s = 0.f;
        for (int g = 0; g < NG; ++g) s += lg[g * OUTC + t];
        float m = s * (1.f / NG);
        float v = 0.f;
        for (int g = 0; g < NG; ++g) { float d = lg[g * OUTC + t] - m; v += d * d; }
        v *= (1.f / NG);
        mu[t] = m;
        inv[t] = rsqrtf(v + EPS) * bn_g[t];
    }
    __syncthreads();

    for (int i = t; i < NG * OUTC; i += blockDim.x) {
        int o = i & (OUTC - 1);
        out[i] = (lg[i] - mu[o]) * inv[o] + bn_b[o];
    }
}

// ---------------------------------------------------------------------------
extern "C" void kernel_launch(void* const* d_in, const int* in_sizes, int n_in,
                              void* d_out, int out_size, void* d_ws, size_t ws_size,
                              hipStream_t stream)
{
    const float* x     = (const float*)d_in[0];
    const int*   ei    = (const int*)  d_in[1];
    const int*   batch = (const int*)  d_in[2];
    const float* W1    = (const float*)d_in[3];
    const float* as1   = (const float*)d_in[4];
    const float* ad1   = (const float*)d_in[5];
    const float* b1    = (const float*)d_in[6];
    const float* ln1g  = (const float*)d_in[7];
    const float* ln1b  = (const float*)d_in[8];
    const float* Wskip = (const float*)d_in[9];
    const float* bskip = (const float*)d_in[10];
    const float* W2    = (const float*)d_in[11];
    const float* as2   = (const float*)d_in[12];
    const float* ad2   = (const float*)d_in[13];
    const float* b2    = (const float*)d_in[14];
    const float* ln2g  = (const float*)d_in[15];
    const float* ln2b  = (const float*)d_in[16];
    const float* Wfc   = (const float*)d_in[17];
    const float* bfc   = (const float*)d_in[18];
    const float* bng   = (const float*)d_in[19];
    const float* bnb   = (const float*)d_in[20];

    const int N  = in_sizes[2];
    const int E  = in_sizes[1] / 2;

    size_t off = 0;
    auto alloc = [&](size_t bytes) -> char* {
        char* p = (char*)d_ws + off;
        off += (bytes + 255) & ~(size_t)255;
        return p;
    };
    unsigned short* Hbuf   = (unsigned short*)alloc((size_t)N * DM * 2);
    unsigned short* xbf    = (unsigned short*)alloc((size_t)N * DM * 2);
    unsigned short* Buf1bf = (unsigned short*)alloc((size_t)N * DM * 2);
    unsigned short* Buf2bf = (unsigned short*)alloc((size_t)N * DM * 2);
    unsigned short* Skipbf = (unsigned short*)alloc((size_t)N * DM * 2);
    float* vbuf   = (float*)alloc((size_t)N * DM * 4);
    float* asrc   = (float*)alloc((size_t)N * NHEAD * 4);
    float* adst   = (float*)alloc((size_t)N * NHEAD * 4);
    int*   cursor = (int*)  alloc((size_t)N * 4);
    unsigned short* col = (unsigned short*)alloc((size_t)N * DCAP * 2);
    unsigned short* wf1 = (unsigned short*)alloc((size_t)2048 * 8 * 2);
    unsigned short* wfs = (unsigned short*)alloc((size_t)2048 * 8 * 2);
    unsigned short* wf2 = (unsigned short*)alloc((size_t)2048 * 8 * 2);
    float* sums   = (float*)alloc((size_t)(NG * DM + NG) * 4);
    float* cnt    = sums + NG * DM;

    const int eb = (E + 255) / 256;
    const int lb = (N + 1) / 2;                 // ln blocks
    const int ab = ((N + 7) / 8) * 8;           // agg_slice blocks (j*8+cs)
    const int xb = (N * DM / 4 + 255) / 256;
    const int cz = (N + 1023) / 1024;
    const int sums_n = NG * DM + NG;
    const int sz = (sums_n + 1023) / 1024;

    // ---- prep: wprep x3 + xprep + cursor-zero + sums-zero ----
    prep_kernel<<<24 + xb + cz + sz, 256, 0, stream>>>(
        W1, Wskip, W2, wf1, wfs, wf2, x, xbf, N * DM, xb,
        cursor, N, sums, sums_n, cz);

    // ---- mega: layer-1 GEMMs + scatter ----
    gemm_scatter_kernel<<<512 + eb, 256, 0, stream>>>(
        xbf, N, wf1, wfs, bskip, as1, ad1, Hbuf, Skipbf, asrc, adst,
        ei, E, cursor, col);

    // ---- layer 1: sliced agg -> LN ----
    agg_slice_kernel<<<ab, 256, 0, stream>>>(cursor, col, Hbuf, asrc, adst,
                                             b1, vbuf, N);
    ln_kernel<<<lb, 128, 0, stream>>>(vbuf, nullptr, ln1g, ln1b, Skipbf,
                                      Buf1bf, N);

    // ---- layer 2 ----
    mfma_gemm_kernel<<<256, 256, 0, stream>>>(Buf1bf, N, wf2, as2, ad2,
                                              Hbuf, asrc, adst);
    agg_slice_kernel<<<ab, 256, 0, stream>>>(cursor, col, Hbuf, asrc, adst,
                                             b2, vbuf, N);
    ln_kernel<<<lb, 128, 0, stream>>>(vbuf, Buf1bf, ln2g, ln2b, nullptr,
                                      Buf2bf, N);

    // ---- pool + head ----
    pool_kernel<<<1024, DM, 0, stream>>>(Buf2bf, batch, N, sums, cnt);
    head_kernel<<<1, 1024, 0, stream>>>(sums, cnt, Wfc, bfc, bng, bnb, (float*)d_out);
}

// Round 19
// 207.174 us; speedup vs baseline: 2.0982x; 2.0982x over previous
//
#include <hip/hip_runtime.h>

#define DM    128
#define NHEAD 2
#define HIDC  64
#define OUTC  32
#define NG    64
#define EPS   1e-5f
#define DCAP  64     // fixed per-dst adjacency capacity (Poisson(16), 12 sigma)

typedef __attribute__((ext_vector_type(8))) short bf16x8;
typedef __attribute__((ext_vector_type(4))) float f32x4;

__device__ __forceinline__ unsigned short f2bf(float f) {
    union { float f; unsigned int u; } v; v.f = f;
    unsigned int r = v.u + 0x7fffu + ((v.u >> 16) & 1u);   // RNE
    return (unsigned short)(r >> 16);
}
__device__ __forceinline__ float bflo(unsigned int u) {
    union { unsigned int u; float f; } v; v.u = u << 16; return v.f;
}
__device__ __forceinline__ float bfhi(unsigned int u) {
    union { unsigned int u; float f; } v; v.u = u & 0xffff0000u; return v.f;
}

// ---------------------------------------------------------------------------
// Prep kernel: [0,24) wprep x3 | [24,24+xb) xprep | cursor-zero | sums-zero.
// ---------------------------------------------------------------------------
__global__ __launch_bounds__(256) void prep_kernel(
    const float* __restrict__ W1, const float* __restrict__ Wskip,
    const float* __restrict__ W2,
    unsigned short* __restrict__ wf1, unsigned short* __restrict__ wfs,
    unsigned short* __restrict__ wf2,
    const float* __restrict__ x, unsigned short* __restrict__ xbf, int total,
    int xb, int* __restrict__ cursor, int N,
    float* __restrict__ sums, int sums_n, int cz)
{
    const int b = blockIdx.x;
    if (b < 24) {
        const float* W = b < 8 ? W1 : (b < 16 ? Wskip : W2);
        unsigned short* WF = b < 8 ? wf1 : (b < 16 ? wfs : wf2);
        const int idx = (b & 7) * 256 + threadIdx.x;    // 0..2047
        const int nt   = idx >> 8;
        const int ks   = (idx >> 6) & 3;
        const int lane = idx & 63;
        const int c    = nt * 16 + (lane & 15);
        const int k0   = ks * 32 + (lane >> 4) * 8;
        bf16x8 f;
#pragma unroll
        for (int j = 0; j < 8; ++j)
            f[j] = (short)f2bf(W[(k0 + j) * DM + c]);
        ((bf16x8*)WF)[idx] = f;
    } else if (b < 24 + xb) {
        const int i = ((b - 24) * 256 + threadIdx.x) * 4;
        if (i < total) {
            const float4 v = *(const float4*)&x[i];
            ushort4 o;
            o.x = f2bf(v.x); o.y = f2bf(v.y); o.z = f2bf(v.z); o.w = f2bf(v.w);
            *(ushort4*)&xbf[i] = o;
        }
    } else if (b < 24 + xb + cz) {
        const int i0 = ((b - 24 - xb) * 256 + threadIdx.x) * 4;
#pragma unroll
        for (int k = 0; k < 4; ++k)
            if (i0 + k < N) cursor[i0 + k] = 0;
    } else {
        const int i0 = ((b - 24 - xb - cz) * 256 + threadIdx.x) * 4;
#pragma unroll
        for (int k = 0; k < 4; ++k)
            if (i0 + k < sums_n) sums[i0 + k] = 0.f;
    }
}

// ---------------------------------------------------------------------------
// MFMA GEMM body: A bf16 row-major, B pre-swizzled frags, bf16 output.
// ---------------------------------------------------------------------------
__device__ __forceinline__ void gemm_body(
    const unsigned short* __restrict__ Xbf, int N,
    const unsigned short* __restrict__ Wfrag,
    const float* __restrict__ bias,
    const float* __restrict__ att_src,
    const float* __restrict__ att_dst,
    unsigned short* __restrict__ Cbf,
    float* __restrict__ a_src,
    float* __restrict__ a_dst,
    int bid, int nblocks)
{
    const int lane = threadIdx.x & 63;
    const int wave = threadIdx.x >> 6;
    const int col  = lane & 15;
    const int kgrp = lane >> 4;

    bf16x8 bfrag[8][4];
    {
        const bf16x8* wf = (const bf16x8*)Wfrag;
#pragma unroll
        for (int nt = 0; nt < 8; ++nt)
#pragma unroll
            for (int ks = 0; ks < 4; ++ks)
                bfrag[nt][ks] = wf[(nt * 4 + ks) * 64 + lane];
    }

    float bcol[8];
#pragma unroll
    for (int nt = 0; nt < 8; ++nt)
        bcol[nt] = bias ? bias[nt * 16 + col] : 0.f;

    float as_c[8], ad_c[8];
    if (att_src) {
#pragma unroll
        for (int nt = 0; nt < 8; ++nt) {
            as_c[nt] = att_src[nt * 16 + col];
            ad_c[nt] = att_dst[nt * 16 + col];
        }
    }

    const int ntiles = (N + 15) >> 4;
    for (int tile = bid * 4 + wave; tile < ntiles; tile += nblocks * 4) {
        const int row0 = tile * 16;

        f32x4 acc[8];
#pragma unroll
        for (int nt = 0; nt < 8; ++nt) acc[nt] = (f32x4){0.f, 0.f, 0.f, 0.f};

        const int r = min(row0 + col, N - 1);
#pragma unroll
        for (int ks = 0; ks < 4; ++ks) {
            const int k0 = ks * 32 + kgrp * 8;
            const bf16x8 af = *(const bf16x8*)&Xbf[(size_t)r * DM + k0];
#pragma unroll
            for (int nt = 0; nt < 8; ++nt)
                acc[nt] = __builtin_amdgcn_mfma_f32_16x16x32_bf16(
                              af, bfrag[nt][ks], acc[nt], 0, 0, 0);
        }

        float dots[4][2], dotd[4][2];
        if (att_src) {
#pragma unroll
            for (int reg = 0; reg < 4; ++reg) {
                dots[reg][0] = dots[reg][1] = 0.f;
                dotd[reg][0] = dotd[reg][1] = 0.f;
            }
        }
#pragma unroll
        for (int reg = 0; reg < 4; ++reg) {
            const int row = row0 + kgrp * 4 + reg;
            const bool ok = row < N;
#pragma unroll
            for (int nt = 0; nt < 8; ++nt) {
                const float o = acc[nt][reg] + bcol[nt];
                if (ok) Cbf[(size_t)row * DM + nt * 16 + col] = f2bf(o);
                if (att_src) {
                    dots[reg][nt >> 2] += o * as_c[nt];
                    dotd[reg][nt >> 2] += o * ad_c[nt];
                }
            }
        }
        if (att_src) {
#pragma unroll
            for (int reg = 0; reg < 4; ++reg) {
#pragma unroll
                for (int h = 0; h < 2; ++h) {
                    float vs = dots[reg][h], vd = dotd[reg][h];
#pragma unroll
                    for (int off = 8; off; off >>= 1) {
                        vs += __shfl_xor(vs, off);
                        vd += __shfl_xor(vd, off);
                    }
                    const int row = row0 + kgrp * 4 + reg;
                    if (col == 0 && row < N) {
                        a_src[row * NHEAD + h] = vs;
                        a_dst[row * NHEAD + h] = vd;
                    }
                }
            }
        }
    }
}

// ---------------------------------------------------------------------------
// Mega kernel: [0,256) H = x@W1 (+att dots) | [256,512) Skip | [512,..) scatter.
// ---------------------------------------------------------------------------
__global__ __launch_bounds__(256) void gemm_scatter_kernel(
    const unsigned short* __restrict__ Xbf, int N,
    const unsigned short* __restrict__ wf1,
    const unsigned short* __restrict__ wfs,
    const float* __restrict__ bskip,
    const float* __restrict__ as1, const float* __restrict__ ad1,
    unsigned short* __restrict__ Hbuf, unsigned short* __restrict__ Skipbf,
    float* __restrict__ a_src, float* __restrict__ a_dst,
    const int* __restrict__ ei, int E,
    int* __restrict__ cursor, unsigned short* __restrict__ col)
{
    const int b = blockIdx.x;
    if (b < 256) {
        gemm_body(Xbf, N, wf1, nullptr, as1, ad1, Hbuf, a_src, a_dst, b, 256);
    } else if (b < 512) {
        gemm_body(Xbf, N, wfs, bskip, nullptr, nullptr, Skipbf,
                  nullptr, nullptr, b - 256, 256);
    } else {
        const int e = (b - 512) * 256 + threadIdx.x;
        if (e < E) {
            const int d = ei[E + e];
            const int k = atomicAdd(&cursor[d], 1);
            if (k < DCAP) col[d * DCAP + k] = (unsigned short)ei[e];
        }
    }
}

// layer 2 GEMM
__global__ __launch_bounds__(256) void mfma_gemm_kernel(
    const unsigned short* __restrict__ Xbf, int N,
    const unsigned short* __restrict__ Wfrag,
    const float* __restrict__ att_src,
    const float* __restrict__ att_dst,
    unsigned short* __restrict__ Cbf,
    float* __restrict__ a_src,
    float* __restrict__ a_dst)
{
    gemm_body(Xbf, N, Wfrag, nullptr, att_src, att_dst, Cbf,
              a_src, a_dst, blockIdx.x, gridDim.x);
}

// ---------------------------------------------------------------------------
// Fused GAT aggregation + bias + (res bf16) + LayerNorm + ELU + (skip bf16).
// One wave per dst node (2/block); emits bf16.
// ---------------------------------------------------------------------------
__global__ __launch_bounds__(128) void gat_agg_ln_kernel(
    const int* __restrict__ deg,
    const unsigned short* __restrict__ col,
    const unsigned short* __restrict__ H,     // bf16
    const float* __restrict__ a_src,
    const float* __restrict__ a_dst,
    const float* __restrict__ bias,
    const unsigned short* __restrict__ res,   // nullable bf16, pre-LN
    const float* __restrict__ lng,
    const float* __restrict__ lnb,
    const unsigned short* __restrict__ skip,  // nullable bf16, post-ELU
    unsigned short* __restrict__ obf,         // bf16 out
    int N)
{
    const int wid  = threadIdx.x >> 6;
    const int d    = blockIdx.x * 2 + wid;
    if (d >= N) return;
    const int lane = threadIdx.x & 63;
    const int half = lane >> 5;
    const int c2   = lane * 2;

    const float ad_h = a_dst[d * NHEAD + half];

    float e0 = a_src[d * NHEAD + half] + ad_h;
    e0 = e0 > 0.f ? e0 : 0.2f * e0;
    const float wself = __expf(e0);
    float den = wself;
    float2 acc;
    {
        const unsigned int hu = *(const unsigned int*)&H[(size_t)d * DM + c2];
        acc.x = wself * bflo(hu);
        acc.y = wself * bfhi(hu);
    }

    const int dg = min(deg[d], DCAP);
    const int p0 = d * DCAP;
    for (int base = 0; base < dg; base += 32) {
        const int m = min(32, dg - base);
        const int el = lane & 31;

        float we = 0.f;
        int s = 0;
        if (el < m) {
            s = (int)col[p0 + base + el];
            float a = a_src[s * NHEAD + half] + ad_h;
            a = a > 0.f ? a : 0.2f * a;
            we = __expf(a);
        }
        float ws = we;
#pragma unroll
        for (int off = 1; off < 32; off <<= 1) ws += __shfl_xor(ws, off);
        den += ws;

        const int hsel = lane & 32;
        int e = 0;
        for (; e + 4 <= m; e += 4) {
            const int s0 = __shfl(s, e),     s1 = __shfl(s, e + 1);
            const int s2 = __shfl(s, e + 2), s3 = __shfl(s, e + 3);
            const float w0 = __shfl(we, hsel | e),       w1 = __shfl(we, hsel | (e + 1));
            const float w2 = __shfl(we, hsel | (e + 2)), w3 = __shfl(we, hsel | (e + 3));
            const unsigned int u0 = *(const unsigned int*)&H[(size_t)s0 * DM + c2];
            const unsigned int u1 = *(const unsigned int*)&H[(size_t)s1 * DM + c2];
            const unsigned int u2 = *(const unsigned int*)&H[(size_t)s2 * DM + c2];
            const unsigned int u3 = *(const unsigned int*)&H[(size_t)s3 * DM + c2];
            acc.x += w0 * bflo(u0) + w1 * bflo(u1) + w2 * bflo(u2) + w3 * bflo(u3);
            acc.y += w0 * bfhi(u0) + w1 * bfhi(u1) + w2 * bfhi(u2) + w3 * bfhi(u3);
        }
        for (; e < m; ++e) {
            const int sE = __shfl(s, e);
            const float wE = __shfl(we, hsel | e);
            const unsigned int uE = *(const unsigned int*)&H[(size_t)sE * DM + c2];
            acc.x += wE * bflo(uE);
            acc.y += wE * bfhi(uE);
        }
    }

    const size_t ibase = (size_t)d * DM + c2;
    const float2 bv = *(const float2*)&bias[c2];
    float vx = acc.x / den + bv.x;
    float vy = acc.y / den + bv.y;
    if (res) {
        const unsigned int ru = *(const unsigned int*)&res[ibase];
        vx += bflo(ru); vy += bfhi(ru);
    }

    float sm = vx + vy;
#pragma unroll
    for (int off = 1; off < 64; off <<= 1) sm += __shfl_xor(sm, off);
    const float mean = sm * (1.f / DM);

    const float dx = vx - mean, dy = vy - mean;
    float s2 = dx * dx + dy * dy;
#pragma unroll
    for (int off = 1; off < 64; off <<= 1) s2 += __shfl_xor(s2, off);
    const float rstd = rsqrtf(s2 * (1.f / DM) + EPS);

    const float2 gv = *(const float2*)&lng[c2];
    const float2 bb = *(const float2*)&lnb[c2];
    float yx = dx * rstd * gv.x + bb.x;
    float yy = dy * rstd * gv.y + bb.y;
    yx = yx > 0.f ? yx : expm1f(yx);
    yy = yy > 0.f ? yy : expm1f(yy);
    if (skip) {
        const unsigned int su = *(const unsigned int*)&skip[ibase];
        yx += bflo(su); yy += bfhi(su);
    }
    const unsigned int pk = (unsigned int)f2bf(yx) |
                            ((unsigned int)f2bf(yy) << 16);
    *(unsigned int*)&obf[ibase] = pk;
}

// ---------------------------------------------------------------------------
// Global mean pool over bf16 emb: sorted batch -> register runs, few atomics.
// ---------------------------------------------------------------------------
__global__ void pool_kernel(const unsigned short* __restrict__ emb,
                            const int* __restrict__ batch, int N,
                            float* __restrict__ sums,
                            float* __restrict__ cnt)
{
    const int t = threadIdx.x;
    const int chunk = (N + gridDim.x - 1) / gridDim.x;
    const int n0 = blockIdx.x * chunk;
    const int n1 = min(N, n0 + chunk);
    if (n0 >= n1) return;

    int cur = batch[n0];
    float acc = 0.f;
    int count = 0;
    for (int n = n0; n < n1; ++n) {
        int b = batch[n];
        if (b != cur) {
            atomicAdd(&sums[cur * DM + t], acc);
            if (t == 0) atomicAdd(&cnt[cur], (float)count);
            acc = 0.f; count = 0; cur = b;
        }
        unsigned short h = emb[(size_t)n * DM + t];
        union { unsigned int u; float f; } v; v.u = ((unsigned int)h) << 16;
        acc += v.f;
        ++count;
    }
    atomicAdd(&sums[cur * DM + t], acc);
    if (t == 0) atomicAdd(&cnt[cur], (float)count);
}

// ---------------------------------------------------------------------------
// Head: graph_emb = sums/cnt; logits = ge @ Wfc + bfc; BatchNorm over graphs.
// ---------------------------------------------------------------------------
__global__ void head_kernel(const float* __restrict__ sums,
                            const float* __restrict__ cnt,
                            const float* __restrict__ Wfc,
                            const float* __restrict__ bfc,
                            const float* __restrict__ bn_g,
                            const float* __restrict__ bn_b,
                            float* __restrict__ out)
{
    __shared__ float ge[NG * DM];
    __shared__ float lg[NG * OUTC];
    __shared__ float mu[OUTC], inv[OUTC];
    const int t = threadIdx.x;

    for (int i = t; i < NG * DM; i += blockDim.x) {
        int g = i >> 7;
        ge[i] = sums[i] / fmaxf(cnt[g], 1.0f);
    }
    __syncthreads();

    for (int i = t; i < NG * OUTC; i += blockDim.x) {
        int g = i >> 5, o = i & (OUTC - 1);
        float acc = bfc[o];
#pragma unroll
        for (int k = 0; k < DM; ++k) acc += ge[g * DM + k] * Wfc[k * OUTC + o];
        lg[i] = acc;
    }
    __syncthreads();

    if (t < OUTC) {
        float s = 0.f;
        for (int g = 0; g < NG; ++g) s += lg[g * OUTC + t];
        float m = s * (1.f / NG);
        float v = 0.f;
        for (int g = 0; g < NG; ++g) { float d = lg[g * OUTC + t] - m; v += d * d; }
        v *= (1.f / NG);
        mu[t] = m;
        inv[t] = rsqrtf(v + EPS) * bn_g[t];
    }
    __syncthreads();

    for (int i = t; i < NG * OUTC; i += blockDim.x) {
        int o = i & (OUTC - 1);
        out[i] = (lg[i] - mu[o]) * inv[o] + bn_b[o];
    }
}

// ---------------------------------------------------------------------------
extern "C" void kernel_launch(void* const* d_in, const int* in_sizes, int n_in,
                              void* d_out, int out_size, void* d_ws, size_t ws_size,
                              hipStream_t stream)
{
    const float* x     = (const float*)d_in[0];
    const int*   ei    = (const int*)  d_in[1];
    const int*   batch = (const int*)  d_in[2];
    const float* W1    = (const float*)d_in[3];
    const float* as1   = (const float*)d_in[4];
    const float* ad1   = (const float*)d_in[5];
    const float* b1    = (const float*)d_in[6];
    const float* ln1g  = (const float*)d_in[7];
    const float* ln1b  = (const float*)d_in[8];
    const float* Wskip = (const float*)d_in[9];
    const float* bskip = (const float*)d_in[10];
    const float* W2    = (const float*)d_in[11];
    const float* as2   = (const float*)d_in[12];
    const float* ad2   = (const float*)d_in[13];
    const float* b2    = (const float*)d_in[14];
    const float* ln2g  = (const float*)d_in[15];
    const float* ln2b  = (const float*)d_in[16];
    const float* Wfc   = (const float*)d_in[17];
    const float* bfc   = (const float*)d_in[18];
    const float* bng   = (const float*)d_in[19];
    const float* bnb   = (const float*)d_in[20];

    const int N  = in_sizes[2];
    const int E  = in_sizes[1] / 2;

    size_t off = 0;
    auto alloc = [&](size_t bytes) -> char* {
        char* p = (char*)d_ws + off;
        off += (bytes + 255) & ~(size_t)255;
        return p;
    };
    unsigned short* Hbuf   = (unsigned short*)alloc((size_t)N * DM * 2);
    unsigned short* xbf    = (unsigned short*)alloc((size_t)N * DM * 2);
    unsigned short* Buf1bf = (unsigned short*)alloc((size_t)N * DM * 2);
    unsigned short* Buf2bf = (unsigned short*)alloc((size_t)N * DM * 2);
    unsigned short* Skipbf = (unsigned short*)alloc((size_t)N * DM * 2);
    float* asrc   = (float*)alloc((size_t)N * NHEAD * 4);
    float* adst   = (float*)alloc((size_t)N * NHEAD * 4);
    int*   cursor = (int*)  alloc((size_t)N * 4);
    unsigned short* col = (unsigned short*)alloc((size_t)N * DCAP * 2);
    unsigned short* wf1 = (unsigned short*)alloc((size_t)2048 * 8 * 2);
    unsigned short* wfs = (unsigned short*)alloc((size_t)2048 * 8 * 2);
    unsigned short* wf2 = (unsigned short*)alloc((size_t)2048 * 8 * 2);
    float* sums   = (float*)alloc((size_t)(NG * DM + NG) * 4);
    float* cnt    = sums + NG * DM;

    const int eb = (E + 255) / 256;
    const int ab = (N + 1) / 2;
    const int xb = (N * DM / 4 + 255) / 256;
    const int cz = (N + 1023) / 1024;
    const int sums_n = NG * DM + NG;
    const int sz = (sums_n + 1023) / 1024;

    // ---- prep: wprep x3 + xprep + cursor-zero + sums-zero (1 launch) ----
    prep_kernel<<<24 + xb + cz + sz, 256, 0, stream>>>(
        W1, Wskip, W2, wf1, wfs, wf2, x, xbf, N * DM, xb,
        cursor, N, sums, sums_n, cz);

    // ---- mega: layer-1 GEMMs + scatter, co-scheduled ----
    gemm_scatter_kernel<<<512 + eb, 256, 0, stream>>>(
        xbf, N, wf1, wfs, bskip, as1, ad1, Hbuf, Skipbf, asrc, adst,
        ei, E, cursor, col);

    // ---- layer 1 agg ----
    gat_agg_ln_kernel<<<ab, 128, 0, stream>>>(cursor, col, Hbuf, asrc, adst,
                                              b1, nullptr, ln1g, ln1b, Skipbf,
                                              Buf1bf, N);

    // ---- layer 2 ----
    mfma_gemm_kernel<<<256, 256, 0, stream>>>(Buf1bf, N, wf2, as2, ad2,
                                              Hbuf, asrc, adst);
    gat_agg_ln_kernel<<<ab, 128, 0, stream>>>(cursor, col, Hbuf, asrc, adst,
                                              b2, Buf1bf, ln2g, ln2b, nullptr,
                                              Buf2bf, N);

    // ---- pool + head ----
    pool_kernel<<<1024, DM, 0, stream>>>(Buf2bf, batch, N, sums, cnt);
    head_kernel<<<1, 1024, 0, stream>>>(sums, cnt, Wfc, bfc, bng, bnb, (float*)d_out);
}